// Round 22
// baseline (7114.808 us; speedup 1.0000x reference)
//
#include <hip/hip_runtime.h>
#include <stdint.h>

#define T_STEPS 256
#define BATCH   8192

// Reference semantics (proven, rounds 16/17/19/21, absmax=0):
//   cur  = sum_k fmaf(w[k], s_k, acc) ascending, single acc; + bias at end
//   mem' = fmaf(0.95, mem, cur) - reset    (reset from OLD mem, {0,1})
//   spike = mem' > 1.0
__device__ __forceinline__ float lif_update(float mem, float cur) {
#pragma clang fp contract(off)
    float reset = (mem > 1.0f) ? 1.0f : 0.0f;
    return fmaf(0.95f, mem, cur) - reset;
}

__device__ __forceinline__ float ubit(uint32_t mask, int k) {
    return (float)((mask >> k) & 1u);
}

#define F2T_STRIDE 49   // float2 per k2-row: 48 lanes + 1 pad

__global__ __launch_bounds__(256, 2)
void snn_kernel(const float* __restrict__ left, const float* __restrict__ right,
                const float* __restrict__ ctx,
                const float* __restrict__ Wl1, const float* __restrict__ bl1,
                const float* __restrict__ Wl2, const float* __restrict__ bl2,
                const float* __restrict__ Wr1, const float* __restrict__ br1,
                const float* __restrict__ Wr2, const float* __restrict__ br2,
                const float* __restrict__ Wc,  const float* __restrict__ bc,
                const float* __restrict__ Wf,  const float* __restrict__ bf,
                const float* __restrict__ Wf2, const float* __restrict__ bf2,
                const float* __restrict__ Wo,  const float* __restrict__ bo,
                float* __restrict__ out)
{
    const int lane  = threadIdx.x & 63;
    const int w_id  = threadIdx.x >> 6;
    const int gwave = blockIdx.x * 4 + w_id;     // 0..4095
    const int b0 = gwave;                        // element 0
    const int b1 = gwave + BATCH / 2;            // element 1

    const int j32 = lane & 31;
    const int jc  = lane & 15;
    const int jf2 = (lane < 48) ? lane : 47;     // lanes 48-63 shadow row
    const int n_o = lane >> 4;

    // ---- LDS: per-wave x per-element spike floats + shared weights ----
    __shared__ __align__(16) float  spk_all[4][2][256];
    __shared__ __align__(16) float2 wf2t[32 * F2T_STRIDE];   // [k2][n] transposed
    __shared__ __align__(16) float  wo_s[4 * 48];

    for (int i = threadIdx.x; i < 32 * 48; i += 256) {
        const int k2 = i / 48, n = i - k2 * 48;
        wf2t[k2 * F2T_STRIDE + n] =
            make_float2(Wf2[n * 64 + 2 * k2], Wf2[n * 64 + 2 * k2 + 1]);
    }
    for (int i = threadIdx.x; i < 4 * 48; i += 256) wo_s[i] = Wo[i];
    __syncthreads();

    float* s0 = spk_all[w_id][0];
    float* s1 = spk_all[w_id][1];
    // region layout (per element): [0,64) l1/r1 ; [64,144) l2|r2|c ;
    //                              [144,208) f ; [208,256) f2
    float* l1f0 = s0,        * l1f1 = s1;
    float* l2c0 = s0 + 64,   * l2c1 = s1 + 64;
    float* ff0  = s0 + 144,  * ff1  = s1 + 144;
    float* f2f0 = s0 + 208,  * f2f1 = s1 + 208;

    // ---- register weights: 121 floats/lane (shared by both elements) ----
    float w1[6], w2[32], wcr[3], wf[80];
    const float* W1row = (lane < 32) ? (Wl1 + lane * 6)  : (Wr1 + j32 * 6);
    const float* W2row = (lane < 32) ? (Wl2 + lane * 32) : (Wr2 + j32 * 32);
    const float  bb1   = (lane < 32) ? bl1[lane] : br1[j32];
    const float  bb2   = (lane < 32) ? bl2[lane] : br2[j32];
#pragma unroll
    for (int k = 0; k < 6;  ++k) w1[k]  = W1row[k];
#pragma unroll
    for (int k = 0; k < 32; ++k) w2[k]  = W2row[k];
#pragma unroll
    for (int k = 0; k < 3;  ++k) wcr[k] = Wc[jc * 3 + k];
    const float bcr  = bc[jc];
#pragma unroll
    for (int k = 0; k < 80; ++k) wf[k]  = Wf[lane * 80 + k];
    const float bfr  = bf[lane];
    const float bf2r = bf2[jf2];
    const float bor  = bo[n_o];
    const float2* wrow2 = &wf2t[jf2];

    // ---- membrane state, 2 elements ----
    float ml1_0 = 0.f, ml2_0 = 0.f, mc_0 = 0.f, mf_0 = 0.f, mf2_0 = 0.f, mo_0 = 0.f;
    float ml1_1 = 0.f, ml2_1 = 0.f, mc_1 = 0.f, mf_1 = 0.f, mf2_1 = 0.f, mo_1 = 0.f;

    for (int t = 0; t < T_STEPS; ++t) {
        const size_t base0 = (size_t)t * BATCH + b0;
        const size_t base1 = (size_t)t * BATCH + b1;

        // ---- packed inputs, one ballot (mapping proven bit-exact in r18) ----
        // e0: left 0-5, ctx 8-10, right 32-37 ; e1: left 16-21, ctx 24-26, right 48-53
        float vin = 0.f;
        if (lane < 6)                     vin = left [base0 * 6 + lane];
        else if (lane >= 16 && lane < 22) vin = left [base1 * 6 + (lane - 16)];
        else if (lane >= 8  && lane < 11) vin = ctx  [base0 * 3 + (lane - 8)];
        else if (lane >= 24 && lane < 27) vin = ctx  [base1 * 3 + (lane - 24)];
        else if (lane >= 32 && lane < 38) vin = right[base0 * 6 + (lane - 32)];
        else if (lane >= 48 && lane < 54) vin = right[base1 * 6 + (lane - 48)];
        const uint64_t in_mask = __ballot(vin > 0.5f);
        const uint32_t inLo = (uint32_t)in_mask;
        const uint32_t side = (lane < 32) ? inLo : (uint32_t)(in_mask >> 32);

        // ---- l1/r1: mask decode, 6 MACs x 2 ----
        {
            const uint32_t m0 = side & 0x3Fu;
            const uint32_t m1 = (side >> 16) & 0x3Fu;
            float a0 = 0.f, a1 = 0.f;
#pragma unroll
            for (int k = 0; k < 6; ++k) {
                a0 = fmaf(w1[k], ubit(m0, k), a0);
                a1 = fmaf(w1[k], ubit(m1, k), a1);
            }
            ml1_0 = lif_update(ml1_0, a0 + bb1);
            ml1_1 = lif_update(ml1_1, a1 + bb1);
        }
        l1f0[lane] = (ml1_0 > 1.0f) ? 1.0f : 0.0f;
        l1f1[lane] = (ml1_1 > 1.0f) ? 1.0f : 0.0f;

        // ---- l2/r2: spikes via LDS b128, weights in regs, 2 chains ----
        {
            const int off = (lane < 32) ? 0 : 32;
            const float4* p0 = reinterpret_cast<const float4*>(l1f0 + off);
            const float4* p1 = reinterpret_cast<const float4*>(l1f1 + off);
            float a0 = 0.f, a1 = 0.f;
#pragma unroll
            for (int q = 0; q < 8; ++q) {
                const float4 x0 = p0[q], x1 = p1[q];
                a0 = fmaf(w2[4*q+0], x0.x, a0);  a1 = fmaf(w2[4*q+0], x1.x, a1);
                a0 = fmaf(w2[4*q+1], x0.y, a0);  a1 = fmaf(w2[4*q+1], x1.y, a1);
                a0 = fmaf(w2[4*q+2], x0.z, a0);  a1 = fmaf(w2[4*q+2], x1.z, a1);
                a0 = fmaf(w2[4*q+3], x0.w, a0);  a1 = fmaf(w2[4*q+3], x1.w, a1);
            }
            ml2_0 = lif_update(ml2_0, a0 + bb2);
            ml2_1 = lif_update(ml2_1, a1 + bb2);
        }
        l2c0[lane] = (ml2_0 > 1.0f) ? 1.0f : 0.0f;
        l2c1[lane] = (ml2_1 > 1.0f) ? 1.0f : 0.0f;

        // ---- c: uniform mask bits (8-10 e0, 24-26 e1 of inLo) ----
        {
            float a0 = 0.f, a1 = 0.f;
#pragma unroll
            for (int k = 0; k < 3; ++k) {
                a0 = fmaf(wcr[k], ubit(inLo, 8 + k),  a0);
                a1 = fmaf(wcr[k], ubit(inLo, 24 + k), a1);
            }
            mc_0 = lif_update(mc_0, a0 + bcr);
            mc_1 = lif_update(mc_1, a1 + bcr);
        }
        if (lane < 16) {
            l2c0[64 + lane] = (mc_0 > 1.0f) ? 1.0f : 0.0f;
            l2c1[64 + lane] = (mc_1 > 1.0f) ? 1.0f : 0.0f;
        }

        // ---- f: 80 MACs x 2, spikes via uniform b128 ----
        {
            const float4* p0 = reinterpret_cast<const float4*>(l2c0);
            const float4* p1 = reinterpret_cast<const float4*>(l2c1);
            float a0 = 0.f, a1 = 0.f;
#pragma unroll
            for (int q = 0; q < 20; ++q) {
                const float4 x0 = p0[q], x1 = p1[q];
                a0 = fmaf(wf[4*q+0], x0.x, a0);  a1 = fmaf(wf[4*q+0], x1.x, a1);
                a0 = fmaf(wf[4*q+1], x0.y, a0);  a1 = fmaf(wf[4*q+1], x1.y, a1);
                a0 = fmaf(wf[4*q+2], x0.z, a0);  a1 = fmaf(wf[4*q+2], x1.z, a1);
                a0 = fmaf(wf[4*q+3], x0.w, a0);  a1 = fmaf(wf[4*q+3], x1.w, a1);
            }
            mf_0 = lif_update(mf_0, a0 + bfr);
            mf_1 = lif_update(mf_1, a1 + bfr);
        }
        ff0[lane] = (mf_0 > 1.0f) ? 1.0f : 0.0f;
        ff1[lane] = (mf_1 > 1.0f) ? 1.0f : 0.0f;

        // ---- f2: 64 MACs x 2, weights from shared LDS (amortized) ----
        {
            const float2* q0 = reinterpret_cast<const float2*>(ff0);
            const float2* q1 = reinterpret_cast<const float2*>(ff1);
            float a0 = 0.f, a1 = 0.f;
#pragma unroll
            for (int k2 = 0; k2 < 32; ++k2) {
                const float2 wv = wrow2[k2 * F2T_STRIDE];
                const float2 x0 = q0[k2], x1 = q1[k2];
                a0 = fmaf(wv.x, x0.x, a0);  a1 = fmaf(wv.x, x1.x, a1);
                a0 = fmaf(wv.y, x0.y, a0);  a1 = fmaf(wv.y, x1.y, a1);
            }
            mf2_0 = lif_update(mf2_0, a0 + bf2r);
            mf2_1 = lif_update(mf2_1, a1 + bf2r);
        }
        if (lane < 48) {
            f2f0[lane] = (mf2_0 > 1.0f) ? 1.0f : 0.0f;
            f2f1[lane] = (mf2_1 > 1.0f) ? 1.0f : 0.0f;
        }

        // ---- o: 48 MACs x 2, wo from LDS float4 (amortized) ----
        {
            const float4* p0  = reinterpret_cast<const float4*>(f2f0);
            const float4* p1  = reinterpret_cast<const float4*>(f2f1);
            const float4* wo4 = reinterpret_cast<const float4*>(&wo_s[n_o * 48]);
            float a0 = 0.f, a1 = 0.f;
#pragma unroll
            for (int q = 0; q < 12; ++q) {
                const float4 w4 = wo4[q];
                const float4 x0 = p0[q], x1 = p1[q];
                a0 = fmaf(w4.x, x0.x, a0);  a1 = fmaf(w4.x, x1.x, a1);
                a0 = fmaf(w4.y, x0.y, a0);  a1 = fmaf(w4.y, x1.y, a1);
                a0 = fmaf(w4.z, x0.z, a0);  a1 = fmaf(w4.z, x1.z, a1);
                a0 = fmaf(w4.w, x0.w, a0);  a1 = fmaf(w4.w, x1.w, a1);
            }
            mo_0 = lif_update(mo_0, a0 + bor);
            mo_1 = lif_update(mo_1, a1 + bor);
            if ((lane & 15) == 0) {
                out[base0 * 4 + n_o] = (mo_0 > 1.0f) ? 1.0f : 0.0f;
                out[base1 * 4 + n_o] = (mo_1 > 1.0f) ? 1.0f : 0.0f;
            }
        }
    }
}

extern "C" void kernel_launch(void* const* d_in, const int* in_sizes, int n_in,
                              void* d_out, int out_size, void* d_ws, size_t ws_size,
                              hipStream_t stream) {
    const float* left  = (const float*)d_in[0];
    const float* right = (const float*)d_in[1];
    const float* ctx   = (const float*)d_in[2];
    const float* Wl1   = (const float*)d_in[3];
    const float* bl1   = (const float*)d_in[4];
    const float* Wl2   = (const float*)d_in[5];
    const float* bl2   = (const float*)d_in[6];
    const float* Wr1   = (const float*)d_in[7];
    const float* br1   = (const float*)d_in[8];
    const float* Wr2   = (const float*)d_in[9];
    const float* br2   = (const float*)d_in[10];
    const float* Wc    = (const float*)d_in[11];
    const float* bc    = (const float*)d_in[12];
    const float* Wf    = (const float*)d_in[13];
    const float* bf    = (const float*)d_in[14];
    const float* Wf2   = (const float*)d_in[15];
    const float* bf2   = (const float*)d_in[16];
    const float* Wo    = (const float*)d_in[17];
    const float* bo    = (const float*)d_in[18];
    float* out = (float*)d_out;

    // 4096 waves x 2 elements each
    hipLaunchKernelGGL(snn_kernel, dim3(1024), dim3(256), 0, stream,
                       left, right, ctx, Wl1, bl1, Wl2, bl2, Wr1, br1, Wr2, br2,
                       Wc, bc, Wf, bf, Wf2, bf2, Wo, bo, out);
}